// Round 2
// baseline (3199.670 us; speedup 1.0000x reference)
//
#include <hip/hip_runtime.h>
#include <stdint.h>

#define BSZ   128
#define PDIM  196
#define EDIM  512
#define HDIM  512
#define ADIM  256
#define VDIM  30000
#define VPAD  30080
#define NSTEP 20
#define KCAT  1536
#define KSTEP 1024
#define NGATE 2048
#define KSPLIT 8

typedef __attribute__((ext_vector_type(8))) short short8;
typedef __attribute__((ext_vector_type(4))) float f32x4;

__device__ __forceinline__ unsigned short f2b(float f) {
  union { float f; uint32_t u; } v; v.f = f;
  uint32_t r = v.u + 0x7fffu + ((v.u >> 16) & 1u);
  return (unsigned short)(r >> 16);
}
__device__ __forceinline__ float b2f(unsigned short u) {
  union { uint32_t u; float f; } v; v.u = ((uint32_t)u) << 16;
  return v.f;
}
__device__ __forceinline__ float ulo(uint32_t u) {
  union { uint32_t u; float f; } v; v.u = u << 16; return v.f;
}
__device__ __forceinline__ float uhi(uint32_t u) {
  union { uint32_t u; float f; } v; v.u = u & 0xffff0000u; return v.f;
}

__device__ __forceinline__ void async16(const void* g, void* l) {
  __builtin_amdgcn_global_load_lds(
      (const __attribute__((address_space(1))) void*)g,
      (__attribute__((address_space(3))) void*)l, 16, 0, 0);
}

// Agent-scope grid barrier: monotonic counter, zeroed by k_init each call.
__device__ __forceinline__ void gsync(unsigned* bar, unsigned target) {
  __threadfence();
  __syncthreads();
  if (threadIdx.x == 0) {
    __hip_atomic_fetch_add(bar, 1u, __ATOMIC_RELEASE, __HIP_MEMORY_SCOPE_AGENT);
    while (__hip_atomic_load(bar, __ATOMIC_ACQUIRE, __HIP_MEMORY_SCOPE_AGENT) < target)
      __builtin_amdgcn_s_sleep(1);
  }
  __syncthreads();
}

// ---------------- setup / conversion kernels ----------------

__global__ void k_cast_f32_bf16(const float* __restrict__ src,
                                unsigned short* __restrict__ dst, int n4) {
  int i = blockIdx.x * 256 + threadIdx.x;
  if (i < n4) {
    float4 v = ((const float4*)src)[i];
    ushort4 o; o.x = f2b(v.x); o.y = f2b(v.y); o.z = f2b(v.z); o.w = f2b(v.w);
    ((ushort4*)dst)[i] = o;
  }
}

__global__ void k_build_wenc_t(const float* __restrict__ W,
                               unsigned short* __restrict__ WT) {
  // W: (512,256) row-major -> WT: (256,512) row-major (bf16)
  int i = blockIdx.x * 256 + threadIdx.x;
  if (i < ADIM * EDIM) {
    int a = i >> 9, k = i & 511;
    WT[i] = f2b(W[k * ADIM + a]);
  }
}

__global__ void k_build_wcat(const float* __restrict__ Wih,
                             const float* __restrict__ Whh,
                             unsigned short* __restrict__ Wcat) {
  int i = blockIdx.x * 256 + threadIdx.x;  // 2048*1536
  if (i < NGATE * KCAT) {
    int n = i / KCAT, k = i - n * KCAT;
    float v = (k < 1024) ? Wih[n * 1024 + k] : Whh[n * 512 + (k - 1024)];
    Wcat[i] = f2b(v);
  }
}

__global__ void k_build_wfc(const float* __restrict__ Wfc,
                            unsigned short* __restrict__ Wp) {
  int i = blockIdx.x * 256 + threadIdx.x;  // 30080*512
  if (i < VPAD * 512) {
    int n = i >> 9, k = i & 511;
    Wp[i] = (n < VDIM) ? f2b(Wfc[n * 512 + k]) : (unsigned short)0;
  }
}

__global__ void k_build_xemb(const int* __restrict__ cap,
                             const float* __restrict__ emb,
                             unsigned short* __restrict__ X) {
  int i = blockIdx.x * 256 + threadIdx.x;  // 20*128*512
  if (i < NSTEP * BSZ * EDIM) {
    int t = i / (BSZ * EDIM);
    int r = i - t * (BSZ * EDIM);
    int b = r >> 9, k = r & 511;
    int tok = cap[b * 21 + t];  // captions[:, :-1]
    X[((size_t)(t * BSZ + b)) * EDIM + k] = f2b(emb[(size_t)tok * EDIM + k]);
  }
}

__global__ void k_build_wdb(const float* __restrict__ Wd,
                            unsigned short* __restrict__ o) {
  int i = blockIdx.x * 256 + threadIdx.x;  // 512*256, same layout
  if (i < HDIM * ADIM) o[i] = f2b(Wd[i]);
}

__global__ void k_init_state(float* __restrict__ cc,
                             unsigned short* __restrict__ XC,
                             unsigned* __restrict__ bar) {
  int i = blockIdx.x * 256 + threadIdx.x;  // 65536
  if (i == 0) *bar = 0u;
  if (i < BSZ * HDIM) {
    cc[i] = 0.f;
    int b = i >> 9, k = i & 511;
    XC[(size_t)b * KSTEP + 512 + k] = 0;  // h-slice for t=0
  }
}

// ---------------- bf16 MFMA GEMM: C = A(MxK) * B(NxK)^T (+bias) ----------------
// 128x128 block tile, BK=32, 256 threads (4 waves). Used for enc_proj / XW / FC.

template <bool OUT_BF16>
__global__ __launch_bounds__(256) void gemm_bt(
    const unsigned short* __restrict__ A, int ldaB,
    const unsigned short* __restrict__ Bm, int ldbB,
    void* __restrict__ C, int ldc, int Nreal,
    const float* __restrict__ bias, int kt, int kchunkB, size_t zstride) {
  __shared__ short As[128 * 32];
  __shared__ short Bs[128 * 32];
  const int tid = threadIdx.x;
  const int w = tid >> 6, lane = tid & 63;
  const int m0 = blockIdx.y * 128, n0 = blockIdx.x * 128;
  const int z = blockIdx.z;

  const char* Ab = (const char*)A + (size_t)z * kchunkB;
  const char* Bb = (const char*)Bm + (size_t)z * kchunkB;

  const int q0 = w, q1 = w + 4;
  const int rr = lane >> 2;
  const int cbyte = (lane & 3) * 16;
  const char* gA0 = Ab + (size_t)(m0 + q0 * 16 + rr) * ldaB + cbyte;
  const char* gA1 = Ab + (size_t)(m0 + q1 * 16 + rr) * ldaB + cbyte;
  const char* gB0 = Bb + (size_t)(n0 + q0 * 16 + rr) * ldbB + cbyte;
  const char* gB1 = Bb + (size_t)(n0 + q1 * 16 + rr) * ldbB + cbyte;
  short* lA0 = &As[q0 * 512]; short* lA1 = &As[q1 * 512];
  short* lB0 = &Bs[q0 * 512]; short* lB1 = &Bs[q1 * 512];

  const int wm = w >> 1, wn = w & 1;
  const int fr = lane & 15, ko = (lane >> 4) * 8;

  f32x4 acc[4][4] = {};

  for (int kb = 0; kb < kt; ++kb) {
    const int kB = kb * 64;
    async16(gA0 + kB, lA0); async16(gA1 + kB, lA1);
    async16(gB0 + kB, lB0); async16(gB1 + kB, lB1);
    __syncthreads();
    short8 af[4], bfr[4];
#pragma unroll
    for (int i = 0; i < 4; ++i)
      af[i] = *(const short8*)&As[(wm * 64 + i * 16 + fr) * 32 + ko];
#pragma unroll
    for (int j = 0; j < 4; ++j)
      bfr[j] = *(const short8*)&Bs[(wn * 64 + j * 16 + fr) * 32 + ko];
#pragma unroll
    for (int i = 0; i < 4; ++i)
#pragma unroll
      for (int j = 0; j < 4; ++j)
        acc[i][j] = __builtin_amdgcn_mfma_f32_16x16x32_bf16(af[i], bfr[j], acc[i][j], 0, 0, 0);
    __syncthreads();
  }

  const int r4 = (lane >> 4) * 4;
  float* Cf = (float*)C + (size_t)z * zstride;
  unsigned short* Cb = (unsigned short*)C;
#pragma unroll
  for (int i = 0; i < 4; ++i) {
#pragma unroll
    for (int j = 0; j < 4; ++j) {
      int cc = n0 + wn * 64 + j * 16 + fr;
      if (cc < Nreal) {
        float bv = bias ? bias[cc] : 0.f;
        int r0 = m0 + wm * 64 + i * 16 + r4;
#pragma unroll
        for (int r = 0; r < 4; ++r) {
          float v = acc[i][j][r] + bv;
          if (OUT_BF16) Cb[(size_t)(r0 + r) * ldc + cc] = f2b(v);
          else          Cf[(size_t)(r0 + r) * ldc + cc] = v;
        }
      }
    }
  }
}

// ---------------- attention phases 2-4 (hp[] must be ready) ----------------

__device__ __forceinline__ void attn_234(
    int b, int tid, int w, int lane, float bf0,
    const unsigned short* __restrict__ EncP,
    const unsigned short* __restrict__ EncB,
    const float* hp, const float* wsh,
    float* ebuf, float* red, float* sred, float* sMS,
    unsigned short* __restrict__ XCdst)
{
  // phase 2: e_p — 4 p-rows per wave pass, per-lane fixed 4-wide a-slice
  const float hpr0 = hp[lane * 4],     hpr1 = hp[lane * 4 + 1];
  const float hpr2 = hp[lane * 4 + 2], hpr3 = hp[lane * 4 + 3];
  const float wsr0 = wsh[lane * 4],     wsr1 = wsh[lane * 4 + 1];
  const float wsr2 = wsh[lane * 4 + 2], wsr3 = wsh[lane * 4 + 3];
  for (int pb = w * 4; pb < PDIM; pb += 32) {
    float s0 = 0.f, s1 = 0.f, s2 = 0.f, s3 = 0.f;
#pragma unroll
    for (int q = 0; q < 4; ++q) {
      int p = pb + q;
      if (p < PDIM) {
        short4 v = *((const short4*)(EncP + (size_t)(b * PDIM + p) * 256) + lane);
        float t0 = fmaxf(b2f((unsigned short)v.x) + hpr0, 0.f) * wsr0;
        float t1 = fmaxf(b2f((unsigned short)v.y) + hpr1, 0.f) * wsr1;
        float t2 = fmaxf(b2f((unsigned short)v.z) + hpr2, 0.f) * wsr2;
        float t3 = fmaxf(b2f((unsigned short)v.w) + hpr3, 0.f) * wsr3;
        float sq = (t0 + t1) + (t2 + t3);
        if (q == 0) s0 = sq; else if (q == 1) s1 = sq;
        else if (q == 2) s2 = sq; else s3 = sq;
      }
    }
#pragma unroll
    for (int off = 32; off; off >>= 1) {
      s0 += __shfl_xor(s0, off, 64);
      s1 += __shfl_xor(s1, off, 64);
      s2 += __shfl_xor(s2, off, 64);
      s3 += __shfl_xor(s3, off, 64);
    }
    if (lane < 4) {
      int p = pb + lane;
      float v = (lane == 0) ? s0 : (lane == 1) ? s1 : (lane == 2) ? s2 : s3;
      if (p < PDIM) ebuf[p] = v + bf0;
    }
  }
  __syncthreads();

  // phase 3: softmax over p
  float m = -1e30f;
  for (int p = tid; p < PDIM; p += 512) m = fmaxf(m, ebuf[p]);
#pragma unroll
  for (int off = 32; off; off >>= 1) m = fmaxf(m, __shfl_down(m, off, 64));
  if (lane == 0) sred[w] = m;
  __syncthreads();
  if (tid == 0) {
    float mm = sred[0];
#pragma unroll
    for (int i = 1; i < 8; ++i) mm = fmaxf(mm, sred[i]);
    sMS[0] = mm;
  }
  __syncthreads();
  const float M = sMS[0];
  float ps = 0.f;
  for (int p = tid; p < PDIM; p += 512) {
    float v = __expf(ebuf[p] - M); ebuf[p] = v; ps += v;
  }
#pragma unroll
  for (int off = 32; off; off >>= 1) ps += __shfl_down(ps, off, 64);
  if (lane == 0) sred[w] = ps;
  __syncthreads();
  if (tid == 0) {
    float ss = 0.f;
#pragma unroll
    for (int i = 0; i < 8; ++i) ss += sred[i];
    sMS[1] = 1.f / ss;
  }
  __syncthreads();
  const float inv = sMS[1];

  // phase 4: context — uint loads (2 cols/thread), p split across thread halves
  {
    const int c2 = tid & 255, ph = tid >> 8;
    const uint32_t* eb = (const uint32_t*)(EncB + (size_t)b * PDIM * 512) + c2;
    float c0 = 0.f, c1 = 0.f, d0 = 0.f, d1 = 0.f;
    const int p0 = ph * 98;
    for (int p = p0; p < p0 + 98; p += 2) {
      float a0 = ebuf[p];     uint32_t u  = eb[(size_t)p * 256];
      c0 = fmaf(a0, ulo(u),  c0); c1 = fmaf(a0, uhi(u),  c1);
      float a1 = ebuf[p + 1]; uint32_t u2 = eb[(size_t)(p + 1) * 256];
      d0 = fmaf(a1, ulo(u2), d0); d1 = fmaf(a1, uhi(u2), d1);
    }
    red[ph * 512 + c2 * 2]     = c0 + d0;
    red[ph * 512 + c2 * 2 + 1] = c1 + d1;
  }
  __syncthreads();
  float v = (red[tid] + red[512 + tid]) * inv;
  XCdst[(size_t)b * KSTEP + tid] = f2b(v);
}

// ---------------- persistent loop kernel ----------------
// 128 blocks x 512 threads, co-resident. Per t:
//   gsync; gates-GEMM (block -> 16 N-tiles x 8 splitK); gsync; cell + attn(t+1).

__global__ __launch_bounds__(512, 1) void k_loop(
    unsigned short* __restrict__ XC,          // NSTEP x 128 x 1024 bf16
    const unsigned short* __restrict__ Wcat,  // 2048 x 1536 bf16
    float* __restrict__ Gpart,                // KSPLIT x 128 x 2048
    const float* __restrict__ XW,             // 2560 x 2048
    const float* __restrict__ bih, const float* __restrict__ bhh,
    float* __restrict__ ccst, unsigned short* __restrict__ Hall,
    const unsigned short* __restrict__ Wdb,   // 512 x 256 bf16
    const float* __restrict__ bd,
    const float* __restrict__ wfull, const float* __restrict__ bfull,
    const unsigned short* __restrict__ EncP,
    const unsigned short* __restrict__ EncB,
    unsigned* __restrict__ bar)
{
  __shared__ short As[128 * 32];
  __shared__ short Bs[128 * 32];
  __shared__ float hsh[512];
  __shared__ float red[1024];
  __shared__ float hp[256];
  __shared__ float wsh[256];
  __shared__ float ebuf[200];
  __shared__ float sred[8];
  __shared__ float sMS[2];

  const int tid = threadIdx.x, blk = blockIdx.x;
  const int w = tid >> 6, lane = tid & 63;
  const int b = blk;                          // cell/attn role
  const int gn0 = (blk >> 3) * 128, gz = blk & 7;  // gemm role
  const float bf0 = bfull[0];
  unsigned bc = 0;

  if (tid < 256) { wsh[tid] = wfull[tid]; hp[tid] = bd[tid]; }
  __syncthreads();

  // attention t=0 (h = 0 -> hproj = bd)
  attn_234(b, tid, w, lane, bf0, EncP, EncB, hp, wsh, ebuf, red, sred, sMS, XC);

  for (int t = 0; t < NSTEP; ++t) {
    gsync(bar, bc += 128);

    // ---- gates GEMM: Gpart[gz][:][gn0:gn0+128] = XCt[:, gz*128:+128] @ Wg^T ----
    {
      const char* Ab = (const char*)(XC + (size_t)t * BSZ * KSTEP) + gz * 256;
      const char* Bb = (const char*)Wcat + 1024 + gz * 256;  // +512 elems k-offset
      const int rr = lane >> 2, cb = (lane & 3) * 16;
      const char* gA = Ab + (size_t)(w * 16 + rr) * (KSTEP * 2) + cb;
      const char* gB = Bb + (size_t)(gn0 + w * 16 + rr) * (KCAT * 2) + cb;
      short* lA = &As[w * 512];
      short* lB = &Bs[w * 512];
      const int wm = w >> 2, wn = w & 3;
      const int fr = lane & 15, ko = (lane >> 4) * 8;
      f32x4 acc[4][2] = {};
#pragma unroll
      for (int kb = 0; kb < 4; ++kb) {
        async16(gA + kb * 64, lA);
        async16(gB + kb * 64, lB);
        __syncthreads();
        short8 af[4], bfr[2];
#pragma unroll
        for (int i = 0; i < 4; ++i)
          af[i] = *(const short8*)&As[(wm * 64 + i * 16 + fr) * 32 + ko];
#pragma unroll
        for (int j = 0; j < 2; ++j)
          bfr[j] = *(const short8*)&Bs[(wn * 32 + j * 16 + fr) * 32 + ko];
#pragma unroll
        for (int i = 0; i < 4; ++i)
#pragma unroll
          for (int j = 0; j < 2; ++j)
            acc[i][j] = __builtin_amdgcn_mfma_f32_16x16x32_bf16(af[i], bfr[j], acc[i][j], 0, 0, 0);
        __syncthreads();
      }
      float* Cz = Gpart + (size_t)gz * BSZ * NGATE;
      const int r4 = (lane >> 4) * 4;
#pragma unroll
      for (int i = 0; i < 4; ++i)
#pragma unroll
        for (int j = 0; j < 2; ++j) {
          int ccol = gn0 + wn * 32 + j * 16 + fr;
          int r0 = wm * 64 + i * 16 + r4;
#pragma unroll
          for (int r = 0; r < 4; ++r)
            Cz[(size_t)(r0 + r) * NGATE + ccol] = acc[i][j][r];
        }
    }

    gsync(bar, bc += 128);

    // ---- cell ----
    unsigned short* XCn = XC + (size_t)(t + 1) * BSZ * KSTEP;  // guarded at t=19
    {
      const int k = tid;
      const float* xw = XW + ((size_t)t * BSZ + b) * NGATE;
      float gI = bih[k]        + bhh[k]        + xw[k];
      float gF = bih[512 + k]  + bhh[512 + k]  + xw[512 + k];
      float gG = bih[1024 + k] + bhh[1024 + k] + xw[1024 + k];
      float gO = bih[1536 + k] + bhh[1536 + k] + xw[1536 + k];
      const float* P = Gpart + (size_t)b * NGATE + k;
#pragma unroll
      for (int z = 0; z < KSPLIT; ++z) {
        const float* Pz = P + (size_t)z * BSZ * NGATE;
        gI += Pz[0]; gF += Pz[512]; gG += Pz[1024]; gO += Pz[1536];
      }
      float cv = ccst[b * 512 + k];
      float ig = 1.f / (1.f + __expf(-gI));
      float fg = 1.f / (1.f + __expf(-gF));
      float gg = tanhf(gG);
      float og = 1.f / (1.f + __expf(-gO));
      float cn = fg * cv + ig * gg;
      float hn = og * tanhf(cn);
      ccst[b * 512 + k] = cn;
      hsh[k] = hn;
      Hall[((size_t)b * NSTEP + t) * 512 + k] = f2b(hn);
      if (t < NSTEP - 1) XCn[(size_t)b * KSTEP + 512 + k] = f2b(hn);
    }
    __syncthreads();

    if (t < NSTEP - 1) {
      // ---- phase 1: hproj = h @ Wdb + bd (bf16 weights, uint-pair loads) ----
      {
        const int p2 = tid & 127, kq = tid >> 7;
        const uint32_t* wrow = (const uint32_t*)Wdb + p2;
        float s0 = 0.f, s1 = 0.f, s2 = 0.f, s3 = 0.f;
        const int k0 = kq * 128;
#pragma unroll 4
        for (int k = k0; k < k0 + 128; k += 2) {
          uint32_t u = wrow[(size_t)k * 128];
          float hv = hsh[k];
          s0 = fmaf(hv, ulo(u), s0); s1 = fmaf(hv, uhi(u), s1);
          uint32_t u2 = wrow[(size_t)(k + 1) * 128];
          float hv2 = hsh[k + 1];
          s2 = fmaf(hv2, ulo(u2), s2); s3 = fmaf(hv2, uhi(u2), s3);
        }
        red[kq * 256 + p2 * 2]     = s0 + s2;
        red[kq * 256 + p2 * 2 + 1] = s1 + s3;
      }
      __syncthreads();
      if (tid < 256)
        hp[tid] = bd[tid] + ((red[tid] + red[256 + tid]) + (red[512 + tid] + red[768 + tid]));
      __syncthreads();

      attn_234(b, tid, w, lane, bf0, EncP, EncB, hp, wsh, ebuf, red, sred, sMS, XCn);
    }
  }
}

// ---------------- launch ----------------

extern "C" void kernel_launch(void* const* d_in, const int* in_sizes, int n_in,
                              void* d_out, int out_size, void* d_ws, size_t ws_size,
                              hipStream_t stream) {
  const float* enc   = (const float*)d_in[0];
  const int*   cap   = (const int*)d_in[1];
  const float* emb   = (const float*)d_in[2];
  const float* Wenc  = (const float*)d_in[3];
  const float* benc  = (const float*)d_in[4];
  const float* Wdec  = (const float*)d_in[5];
  const float* bdec  = (const float*)d_in[6];
  const float* wfull = (const float*)d_in[7];
  const float* bfull = (const float*)d_in[8];
  const float* Wih   = (const float*)d_in[9];
  const float* bih   = (const float*)d_in[10];
  const float* Whh   = (const float*)d_in[11];
  const float* bhh   = (const float*)d_in[12];
  const float* Wfc   = (const float*)d_in[13];
  const float* bfc   = (const float*)d_in[14];
  float* out = (float*)d_out;

  char* ws = (char*)d_ws;
  size_t off = 0;
  auto alloc = [&](size_t bytes) {
    char* p = ws + off;
    off += (bytes + 255) & ~(size_t)255;
    return p;
  };
  unsigned short* Wcat  = (unsigned short*)alloc((size_t)NGATE * KCAT * 2);
  unsigned short* Wfcb  = (unsigned short*)alloc((size_t)VPAD * 512 * 2);
  unsigned short* WencT = (unsigned short*)alloc((size_t)ADIM * EDIM * 2);
  unsigned short* EncB  = (unsigned short*)alloc((size_t)BSZ * PDIM * EDIM * 2);
  unsigned short* EncP  = (unsigned short*)alloc((size_t)BSZ * PDIM * ADIM * 2);
  unsigned short* XC    = (unsigned short*)alloc((size_t)NSTEP * BSZ * KSTEP * 2);
  unsigned short* Xemb  = (unsigned short*)alloc((size_t)NSTEP * BSZ * EDIM * 2);
  float* XW             = (float*)alloc((size_t)NSTEP * BSZ * NGATE * 4);
  float* Gpart          = (float*)alloc((size_t)KSPLIT * BSZ * NGATE * 4);
  float* ccst           = (float*)alloc((size_t)BSZ * HDIM * 4);
  unsigned short* Hall  = (unsigned short*)alloc((size_t)NSTEP * BSZ * HDIM * 2);
  unsigned short* Wdb   = (unsigned short*)alloc((size_t)HDIM * ADIM * 2);
  unsigned* bar         = (unsigned*)alloc(256);
  (void)ws_size; (void)in_sizes; (void)n_in; (void)out_size;

  // setup
  {
    int n4 = BSZ * PDIM * EDIM / 4;
    k_cast_f32_bf16<<<(n4 + 255) / 256, 256, 0, stream>>>(enc, EncB, n4);
  }
  k_build_wenc_t<<<(ADIM * EDIM + 255) / 256, 256, 0, stream>>>(Wenc, WencT);
  k_build_wcat<<<(NGATE * KCAT + 255) / 256, 256, 0, stream>>>(Wih, Whh, Wcat);
  k_build_wfc<<<(VPAD * 512 + 255) / 256, 256, 0, stream>>>(Wfc, Wfcb);
  k_build_xemb<<<(NSTEP * BSZ * EDIM + 255) / 256, 256, 0, stream>>>(cap, emb, Xemb);
  k_build_wdb<<<(HDIM * ADIM + 255) / 256, 256, 0, stream>>>(Wdec, Wdb);
  k_init_state<<<(BSZ * HDIM + 255) / 256, 256, 0, stream>>>(ccst, XC, bar);

  // enc_proj: (25088x256 bf16) = EncB(25088x512) @ WencT(256x512)^T + benc
  gemm_bt<true><<<dim3(2, 196, 1), 256, 0, stream>>>(
      EncB, EDIM * 2, WencT, EDIM * 2, EncP, ADIM, ADIM, benc, 16, 0, 0);

  // XW: (2560x2048) = Xemb(2560x512) @ Wcat[:, :512]^T  (xt contribution, all steps)
  gemm_bt<false><<<dim3(NGATE / 128, NSTEP * BSZ / 128, 1), 256, 0, stream>>>(
      Xemb, EDIM * 2, Wcat, KCAT * 2, XW, NGATE, NGATE, nullptr, 16, 0, 0);

  // persistent 20-step loop (attn0 + 20x{gates GEMM, cell+attn})
  k_loop<<<128, 512, 0, stream>>>(XC, Wcat, Gpart, XW, bih, bhh, ccst, Hall,
                                  Wdb, bdec, wfull, bfull, EncP, EncB, bar);

  // FC head: out(2560x30000) = Hall(2560x512) @ Wfcb(30080x512)^T + bfc
  gemm_bt<false><<<dim3(VPAD / 128, NSTEP * BSZ / 128, 1), 256, 0, stream>>>(
      Hall, HDIM * 2, Wfcb, HDIM * 2, out, VDIM, VDIM, bfc, 16, 0, 0);
}